// Round 14
// baseline (188.092 us; speedup 1.0000x reference)
//
#include <hip/hip_runtime.h>

#define PI_F 3.14159265358979323846f
#define HWSZ 4096   // H*W
#define NPIX 8192   // B*H*W

typedef __attribute__((ext_vector_type(8))) short short8;
typedef __attribute__((ext_vector_type(4))) short short4_t;
typedef __attribute__((ext_vector_type(4))) float f32x4;

__device__ __forceinline__ short f2bf(float x){
  unsigned u = __float_as_uint(x);
  unsigned r = (u + 0x7FFFu + ((u >> 16) & 1u)) >> 16;
  return (short)r;
}
__device__ __forceinline__ float bf2f(short v){
  return __uint_as_float(((unsigned)(unsigned short)v) << 16);
}

__device__ __forceinline__ float wsum64(float v){
  #pragma unroll
  for (int m = 32; m >= 1; m >>= 1) v += __shfl_xor(v, m, 64);
  return v;
}
__device__ __forceinline__ float wsum8(float v){
  v += __shfl_xor(v, 1, 64);
  v += __shfl_xor(v, 2, 64);
  v += __shfl_xor(v, 4, 64);
  return v;
}

// async global->LDS, 16B per lane.
__device__ __forceinline__ void gl_lds(const short* g, short* s){
  __builtin_amdgcn_global_load_lds(
      (const __attribute__((address_space(1))) unsigned int*)g,
      (__attribute__((address_space(3))) unsigned int*)s, 16, 0, 0);
}

// ---------------- merged prep + layout kernel (sectioned by blockIdx.x) ----------------
// sec0 [0,130): zero enh_pad RING only ; sec1 [130,386): dc_w->Bdc ;
// sec2 [386,642): op_w1->B2op ; sec3 [642,1282): apw3 ; sec4 [1282,2210): cast x2 ;
// sec5 [2210,4258): nchw_split
__global__ void k_prepall(const float* __restrict__ dc_w, const float* __restrict__ op_w1,
    const float* __restrict__ ap_w1, const float* __restrict__ features,
    const float* __restrict__ s0, const float* __restrict__ s1,
    const float* __restrict__ s2, const float* __restrict__ s3, const float* __restrict__ s4,
    short* __restrict__ enh_pad, short* __restrict__ Bdc, short* __restrict__ B2op,
    short* __restrict__ B3, short* __restrict__ A3,
    short* __restrict__ d0, short* __restrict__ d1,
    short* __restrict__ d2, short* __restrict__ d3, short* __restrict__ d4){
  __shared__ short tile[2304];
  __shared__ float ft[32][33];
  int bx = blockIdx.x, tid = threadIdx.x;
  if (bx < 130){
    int i = bx*256 + tid;           // short4 index over ring pixels [0, 33280)
    if (i < 33280){
      int px = i >> 6;              // 0..519
      int c4 = (i & 63) * 4;
      int b = px >= 260 ? 1 : 0;
      int r = px - b*260;
      int row, col;
      if (r < 66){ row = 0; col = r; }
      else if (r < 132){ row = 65; col = r - 66; }
      else { int rr = r - 132; row = (rr >> 1) + 1; col = (rr & 1)*65; }
      int pp = b*4356 + row*66 + col;
      *(short4_t*)(enh_pad + (size_t)pp*256 + c4) = (short4_t){0,0,0,0};
    }
  } else if (bx < 386){
    int o = bx - 130;
    const float* wo = dc_w + (size_t)o*2304;
    for (int i = tid; i < 2304; i += 256){
      int c = i / 9, k = i - c*9;
      tile[k*256 + c] = f2bf(wo[i]);
    }
    __syncthreads();
    for (int i = tid; i < 2304; i += 256){
      int k = i >> 8, c = i & 255;
      Bdc[((size_t)(k*256 + o))*256 + c] = tile[i];
    }
  } else if (bx < 642){
    int o = bx - 386;
    const float* wo = op_w1 + (size_t)o*2304;
    for (int i = tid; i < 2304; i += 256){
      int c = i / 9, k = i - c*9;
      tile[k*256 + c] = f2bf(wo[i]);
    }
    __syncthreads();
    short* out = B2op + (size_t)o*2304;
    for (int i = tid; i < 2304; i += 256) out[i] = tile[i];
  } else if (bx < 1282){
    int n = bx - 642, c = tid;
    short hi = 0;
    if (n < 576){
      int o = n & 63, k = n >> 6;
      hi = f2bf(ap_w1[((size_t)o*256 + c)*9 + k]);
    }
    B3[(size_t)n*512 + c] = hi;
    B3[(size_t)n*512 + 256 + c] = hi;
  } else if (bx < 2210){
    int i = (bx - 1282)*512 + tid;
    #pragma unroll
    for (int rep = 0; rep < 2; ++rep){
      if (i < 196608) d0[i] = f2bf(s0[i]);
      else if (i < 262144) d1[i-196608] = f2bf(s1[i-196608]);
      else if (i < 344064) d2[i-262144] = f2bf(s2[i-262144]);
      else if (i < 409600) d3[i-344064] = f2bf(s3[i-344064]);
      else if (i < 475136) d4[i-409600] = f2bf(s4[i-409600]);
      i += 256;
    }
  } else {
    int bid = bx - 2210;
    int z = bid >> 10;
    int rem = bid & 1023;
    int p0 = (rem & 127)*32, c0 = (rem >> 7)*32;
    int tx = tid & 31, ty = tid >> 5;
    #pragma unroll
    for (int i = ty; i < 32; i += 8)
      ft[i][tx] = features[((size_t)z*256 + c0 + i)*HWSZ + p0 + tx];
    __syncthreads();
    #pragma unroll
    for (int i = ty; i < 32; i += 8){
      float x = ft[tx][i];
      short hi = f2bf(x);
      short lo = f2bf(x - bf2f(hi));
      size_t p = (size_t)z*HWSZ + p0 + i;
      A3[p*512 + c0 + tx] = hi;
      A3[p*512 + 256 + c0 + tx] = lo;
    }
  }
}

// ---------------- merged front-end GEMM: G (tap-planar) + T_ap, one dispatch ----------
// grid (64, 23). y<18: G = A3.hi x Bdc^T (K=256) -> planar [9][8192][256] bf16
//                y>=18: T = A3 x B3^T (K=512) -> fp32 (8192,640)
__global__ __launch_bounds__(256) void k_mainA(const short* __restrict__ A3,
    const short* __restrict__ Bdc, const short* __restrict__ B3,
    short* __restrict__ G, float* __restrict__ T){
  __shared__ alignas(16) short sA[2][128*32];
  __shared__ alignas(16) short sB[2][128*32];
  bool isG = blockIdx.y < 18;
  const short* B; int K, ldb, n0;
  if (isG){ B = Bdc; K = 256; ldb = 256; n0 = blockIdx.y*128; }
  else    { B = B3;  K = 512; ldb = 512; n0 = ((int)blockIdx.y - 18)*128; }
  int tid = threadIdx.x;
  int w = tid >> 6, l = tid & 63;
  int wc = w & 1, wr = w >> 1;
  int ml = l & 15, g = l >> 4;
  int srow = tid >> 2;
  int sch = (tid & 3)*8;
  int m0 = blockIdx.x*128;
  const short* Agp = A3 + (size_t)(m0 + srow)*512 + sch;
  const short* Bgp = B + (size_t)(n0 + srow)*ldb + sch;
  short* sAd = &sA[0][srow*32 + sch];
  short* sBd = &sB[0][srow*32 + sch];
  f32x4 acc[4][4];
  #pragma unroll
  for (int i = 0; i < 4; ++i)
    #pragma unroll
    for (int j = 0; j < 4; ++j) acc[i][j] = (f32x4){0.f,0.f,0.f,0.f};
  #define STG(bf, kt) { \
    gl_lds(Agp + (kt)*32, sAd + (bf)*4096); \
    gl_lds(Agp + (size_t)64*512 + (kt)*32, sAd + (bf)*4096 + 2048); \
    gl_lds(Bgp + (kt)*32, sBd + (bf)*4096); \
    gl_lds(Bgp + (size_t)64*ldb + (kt)*32, sBd + (bf)*4096 + 2048); \
  }
  int nk = K >> 5;
  STG(0, 0)
  int buf = 0;
  for (int kt = 0; kt < nk; ++kt){
    __syncthreads();
    if (kt + 1 < nk){ STG(buf^1, kt+1) }
    short8 af[4], bq[4];
    #pragma unroll
    for (int i = 0; i < 4; ++i)
      af[i] = *(const short8*)&sA[buf][(wr*64 + i*16 + ml)*32 + g*8];
    #pragma unroll
    for (int j = 0; j < 4; ++j)
      bq[j] = *(const short8*)&sB[buf][(wc*64 + j*16 + ml)*32 + g*8];
    #pragma unroll
    for (int i = 0; i < 4; ++i)
      #pragma unroll
      for (int j = 0; j < 4; ++j)
        acc[i][j] = __builtin_amdgcn_mfma_f32_16x16x32_bf16(af[i], bq[j], acc[i][j], 0, 0, 0);
    buf ^= 1;
  }
  #undef STG
  int m0w = m0 + wr*64;
  int n0w = n0 + wc*64;
  #pragma unroll
  for (int fm = 0; fm < 4; ++fm)
    #pragma unroll
    for (int fn = 0; fn < 4; ++fn)
      #pragma unroll
      for (int r = 0; r < 4; ++r){
        int row = m0w + fm*16 + g*4 + r;
        int col = n0w + fn*16 + ml;
        float v = acc[fm][fn][r];
        if (isG)
          G[(size_t)(col>>8)*2097152 + (size_t)row*256 + (col&255)] = f2bf(v);
        else
          T[(size_t)row*640 + col] = v;
      }
}

// ---------------- LDS-staged bf16 TN GEMM template (small-N chain) ----------------
// EPI: 2 bf16 relu+bias; 6 gate->padded NHWC
template<int EPI, int BM, int BN = 128>
__global__ __launch_bounds__(256) void k_gemml(const short* __restrict__ A,
    const short* __restrict__ B, void* __restrict__ Cv,
    const float* __restrict__ bias, const short* __restrict__ aux,
    int K, int ldc){
  constexpr int NWC = BN/64;
  constexpr int NWR = 4/NWC;
  constexpr int WM = BM/NWR;
  constexpr int AF = WM/16;
  __shared__ alignas(16) short sA[2][BM*32];
  __shared__ alignas(16) short sB[2][BN*32];
  int tid = threadIdx.x;
  int w = tid >> 6, l = tid & 63;
  int wc = w % NWC, wr = w / NWC;
  int ml = l & 15, g = l >> 4;
  int srow = tid >> 2;
  int sch = (tid & 3)*8;
  int m0 = blockIdx.x*BM, n0 = blockIdx.y*BN;
  const short* Agp = A + (size_t)(m0 + srow)*K + sch;
  const short* Bgp = B + (size_t)(n0 + srow)*K + sch;
  short* sAd = &sA[0][srow*32 + sch];
  short* sBd = &sB[0][srow*32 + sch];
  f32x4 acc[AF][4];
  #pragma unroll
  for (int i = 0; i < AF; ++i)
    #pragma unroll
    for (int j = 0; j < 4; ++j) acc[i][j] = (f32x4){0.f,0.f,0.f,0.f};

  #define STAGE(bf, kt) { \
    _Pragma("unroll") \
    for (int c = 0; c < BM/64; ++c) \
      gl_lds(Agp + (size_t)(c*64)*K + (kt)*32, sAd + (bf)*BM*32 + c*2048); \
    _Pragma("unroll") \
    for (int c = 0; c < BN/64; ++c) \
      gl_lds(Bgp + (size_t)(c*64)*K + (kt)*32, sBd + (bf)*BN*32 + c*2048); \
  }
  int nk = K >> 5;
  STAGE(0, 0)
  int buf = 0;
  for (int kt = 0; kt < nk; ++kt){
    __syncthreads();
    if (kt + 1 < nk){ STAGE(buf^1, kt+1) }
    short8 af[AF], bq[4];
    #pragma unroll
    for (int i = 0; i < AF; ++i)
      af[i] = *(const short8*)&sA[buf][(wr*WM + i*16 + ml)*32 + g*8];
    #pragma unroll
    for (int j = 0; j < 4; ++j)
      bq[j] = *(const short8*)&sB[buf][(wc*64 + j*16 + ml)*32 + g*8];
    #pragma unroll
    for (int i = 0; i < AF; ++i)
      #pragma unroll
      for (int j = 0; j < 4; ++j)
        acc[i][j] = __builtin_amdgcn_mfma_f32_16x16x32_bf16(af[i], bq[j], acc[i][j], 0, 0, 0);
    buf ^= 1;
  }
  #undef STAGE

  int m0w = m0 + wr*WM;
  int n0w = n0 + wc*64;
  #pragma unroll
  for (int fm = 0; fm < AF; ++fm)
    #pragma unroll
    for (int fn = 0; fn < 4; ++fn)
      #pragma unroll
      for (int r = 0; r < 4; ++r){
        int row = m0w + fm*16 + g*4 + r;
        int col = n0w + fn*16 + ml;
        float v = acc[fm][fn][r];
        if constexpr (EPI == 2){
          ((short*)Cv)[(size_t)row*ldc + col] = f2bf(fmaxf(v + bias[col], 0.f));
        } else if constexpr (EPI == 6){
          float f = bf2f(aux[(size_t)row*320 + col]);
          float s = 1.f/(1.f + __expf(-(v + bias[col])));
          int b = row >> 12, hw = row & 4095;
          int pi = b*4356 + ((hw>>6)+1)*66 + (hw&63) + 1;
          ((short*)Cv)[(size_t)pi*256 + col] = f2bf(f * (1.f + s));
        }
      }
}

// ---------------- merged Q + KV projection GEMM (one dispatch) ----------------
__global__ __launch_bounds__(256) void k_qkv(const short* __restrict__ cand,
    const short* __restrict__ inw, const float* __restrict__ inb,
    short* __restrict__ KV, short* __restrict__ Qb){
  const short* A; const short* B; short* C; const float* bias; int ldc, m0, n0;
  if (blockIdx.y < 4){
    A = cand; B = inw + (size_t)256*256; C = KV; bias = inb + 256; ldc = 512;
    m0 = blockIdx.x*128; n0 = blockIdx.y*128;
  } else {
    if (blockIdx.x >= 128) return;
    A = cand + (size_t)NPIX*256; B = inw; C = Qb; bias = inb; ldc = 256;
    m0 = (blockIdx.x >> 1)*128; n0 = (blockIdx.x & 1)*128;
  }
  __shared__ alignas(16) short sA[2][128*32];
  __shared__ alignas(16) short sB[2][128*32];
  int tid = threadIdx.x;
  int w = tid >> 6, l = tid & 63;
  int wc = w & 1, wr = w >> 1;
  int ml = l & 15, g = l >> 4;
  int srow = tid >> 2;
  int sch = (tid & 3)*8;
  const short* Agp = A + (size_t)(m0 + srow)*256 + sch;
  const short* Bgp = B + (size_t)(n0 + srow)*256 + sch;
  short* sAd = &sA[0][srow*32 + sch];
  short* sBd = &sB[0][srow*32 + sch];
  f32x4 acc[4][4];
  #pragma unroll
  for (int i = 0; i < 4; ++i)
    #pragma unroll
    for (int j = 0; j < 4; ++j) acc[i][j] = (f32x4){0.f,0.f,0.f,0.f};
  #define STG2(bf, kt) { \
    gl_lds(Agp + (kt)*32, sAd + (bf)*4096); \
    gl_lds(Agp + (size_t)64*256 + (kt)*32, sAd + (bf)*4096 + 2048); \
    gl_lds(Bgp + (kt)*32, sBd + (bf)*4096); \
    gl_lds(Bgp + (size_t)64*256 + (kt)*32, sBd + (bf)*4096 + 2048); \
  }
  STG2(0, 0)
  int buf = 0;
  for (int kt = 0; kt < 8; ++kt){
    __syncthreads();
    if (kt + 1 < 8){ STG2(buf^1, kt+1) }
    short8 af[4], bq[4];
    #pragma unroll
    for (int i = 0; i < 4; ++i)
      af[i] = *(const short8*)&sA[buf][(wr*64 + i*16 + ml)*32 + g*8];
    #pragma unroll
    for (int j = 0; j < 4; ++j)
      bq[j] = *(const short8*)&sB[buf][(wc*64 + j*16 + ml)*32 + g*8];
    #pragma unroll
    for (int i = 0; i < 4; ++i)
      #pragma unroll
      for (int j = 0; j < 4; ++j)
        acc[i][j] = __builtin_amdgcn_mfma_f32_16x16x32_bf16(af[i], bq[j], acc[i][j], 0, 0, 0);
    buf ^= 1;
  }
  #undef STG2
  int m0w = m0 + wr*64;
  int n0w = n0 + wc*64;
  #pragma unroll
  for (int fm = 0; fm < 4; ++fm)
    #pragma unroll
    for (int fn = 0; fn < 4; ++fn)
      #pragma unroll
      for (int r = 0; r < 4; ++r){
        int row = m0w + fm*16 + g*4 + r;
        int col = n0w + fn*16 + ml;
        C[(size_t)row*ldc + col] = f2bf(acc[fm][fn][r] + bias[col]);
      }
}

// ---------------- attention core fused with output projection ----------------
__global__ __launch_bounds__(256) void k_attnproj(const short* __restrict__ Qb,
    const short* __restrict__ KVb, const short* __restrict__ wot,
    const float* __restrict__ outb, short* __restrict__ gateA){
  __shared__ alignas(16) short sO[64*256];
  __shared__ alignas(16) short sB[2][64*32];
  int tid = threadIdx.x;
  int m0 = blockIdx.x*64, n0 = blockIdx.y*64;
  int srow = tid >> 2, sch = (tid & 3)*8;
  const short* Bgp = wot + (size_t)(n0 + srow)*256 + sch;
  short* sBd = &sB[0][srow*32 + sch];
  gl_lds(Bgp, sBd);                 // first B stage overlaps attn compute
  int lane = tid & 63;
  int sub = tid >> 6;
  const float sc = 0.17677669529663688f; // 1/sqrt(32)
  #pragma unroll 2
  for (int it = 0; it < 16; ++it){
    int lp = it*4 + sub;
    int p = m0 + lp;
    float q[4];
    { short4_t t = *(const short4_t*)(Qb + (size_t)p*256 + lane*4);
      #pragma unroll
      for (int j = 0; j < 4; ++j) q[j] = bf2f(t[j]); }
    float kv[3][2][4];
    #pragma unroll
    for (int i = 0; i < 3; ++i){
      const short* rp = KVb + (size_t)(i*NPIX + p)*512 + lane*4;
      short4_t kt = *(const short4_t*)rp;
      short4_t vt = *(const short4_t*)(rp + 256);
      #pragma unroll
      for (int j = 0; j < 4; ++j){ kv[i][0][j] = bf2f(kt[j]); kv[i][1][j] = bf2f(vt[j]); }
    }
    float s[3];
    #pragma unroll
    for (int i = 0; i < 3; ++i){
      float d = 0.f;
      #pragma unroll
      for (int j = 0; j < 4; ++j) d = fmaf(q[j], kv[i][0][j], d);
      s[i] = wsum8(d) * sc;
    }
    float m = fmaxf(s[0], fmaxf(s[1], s[2]));
    float e0 = __expf(s[0]-m), e1 = __expf(s[1]-m), e2 = __expf(s[2]-m);
    float inv = 1.f/(e0+e1+e2);
    short4_t ot;
    #pragma unroll
    for (int j = 0; j < 4; ++j)
      ot[j] = f2bf((e0*kv[0][1][j] + e1*kv[1][1][j] + e2*kv[2][1][j]) * inv);
    *(short4_t*)&sO[lp*256 + lane*4] = ot;
  }
  // GEMM: A = sO (64x256), B = wot rows [n0,n0+64), 8 K-steps
  int w = sub, ml = lane & 15, g = lane >> 4;
  f32x4 acc[4];
  #pragma unroll
  for (int j = 0; j < 4; ++j) acc[j] = (f32x4){0.f,0.f,0.f,0.f};
  int buf = 0;
  for (int kt = 0; kt < 8; ++kt){
    __syncthreads();
    if (kt + 1 < 8) gl_lds(Bgp + (kt+1)*32, sBd + (buf^1)*2048);
    short8 af = *(const short8*)&sO[(w*16 + ml)*256 + kt*32 + g*8];
    short8 bq[4];
    #pragma unroll
    for (int j = 0; j < 4; ++j)
      bq[j] = *(const short8*)&sB[buf][(j*16 + ml)*32 + g*8];
    #pragma unroll
    for (int j = 0; j < 4; ++j)
      acc[j] = __builtin_amdgcn_mfma_f32_16x16x32_bf16(af, bq[j], acc[j], 0, 0, 0);
    buf ^= 1;
  }
  int m0w = m0 + w*16;
  #pragma unroll
  for (int fn = 0; fn < 4; ++fn)
    #pragma unroll
    for (int r = 0; r < 4; ++r){
      int row = m0w + g*4 + r;
      int col = n0 + fn*16 + ml;
      gateA[(size_t)row*320 + col] = f2bf(acc[fn][r] + outb[col]);
    }
}

// ---------------- implicit-GEMM 3x3 conv, LDS-staged, split-K=2 (taps 0-4 / 5-8) ------
__global__ __launch_bounds__(256) void k_igconv(const short* __restrict__ Xpad,
    const short* __restrict__ B2, float* __restrict__ PG){
  __shared__ alignas(16) short sA[2][64*32];
  __shared__ alignas(16) short sB[2][128*32];
  int zg = blockIdx.z;
  int tapb = zg ? 5 : 0;
  int nk = zg ? 32 : 40;
  int tid = threadIdx.x;
  int w = tid >> 6, l = tid & 63;
  int wr = w & 1, wc = w >> 1;
  int ml = l & 15, g = l >> 4;
  int srow = tid >> 2;
  int sch = (tid & 3)*8;
  int m0 = blockIdx.x*64, n0 = blockIdx.y*128;
  int b = blockIdx.x >> 6, imgrow = blockIdx.x & 63;
  int qbase = b*4356 + (imgrow+1)*66 + srow + 1;
  const short* Bgp = B2 + (size_t)(n0 + srow)*2304 + tapb*256 + sch;
  short* sAd = &sA[0][srow*32 + sch];
  short* sBd = &sB[0][srow*32 + sch];
  int toff[5];
  #pragma unroll
  for (int i = 0; i < 5; ++i){
    int t = tapb + i;
    if (t < 9) toff[i] = (t/3 - 1)*66 + (t%3) - 1;
    else toff[i] = 0;
  }
  f32x4 acc[2][4];
  #pragma unroll
  for (int i = 0; i < 2; ++i)
    #pragma unroll
    for (int j = 0; j < 4; ++j) acc[i][j] = (f32x4){0.f,0.f,0.f,0.f};

  #define STG(bf, kt) { \
    int tap = (kt) >> 3, cofs = ((kt) & 7)*32; \
    gl_lds(Xpad + (size_t)(qbase + toff[tap])*256 + cofs + sch, sAd + (bf)*2048); \
    gl_lds(Bgp + (kt)*32, sBd + (bf)*4096); \
    gl_lds(Bgp + (size_t)64*2304 + (kt)*32, sBd + (bf)*4096 + 2048); \
  }
  STG(0, 0)
  int buf = 0;
  for (int kt = 0; kt < nk; ++kt){
    __syncthreads();
    if (kt < nk - 1){ STG(buf^1, kt+1) }
    short8 af[2], bq[4];
    #pragma unroll
    for (int i = 0; i < 2; ++i)
      af[i] = *(const short8*)&sA[buf][(wr*32 + i*16 + ml)*32 + g*8];
    #pragma unroll
    for (int j = 0; j < 4; ++j)
      bq[j] = *(const short8*)&sB[buf][(wc*64 + j*16 + ml)*32 + g*8];
    #pragma unroll
    for (int i = 0; i < 2; ++i)
      #pragma unroll
      for (int j = 0; j < 4; ++j)
        acc[i][j] = __builtin_amdgcn_mfma_f32_16x16x32_bf16(af[i], bq[j], acc[i][j], 0, 0, 0);
    buf ^= 1;
  }
  #undef STG

  float* out = PG + (size_t)zg*2097152;
  int m0w = m0 + wr*32;
  int n0w = n0 + wc*64;
  #pragma unroll
  for (int fm = 0; fm < 2; ++fm)
    #pragma unroll
    for (int fn = 0; fn < 4; ++fn)
      #pragma unroll
      for (int r = 0; r < 4; ++r){
        int row = m0w + fm*16 + g*4 + r;
        int col = n0w + fn*16 + ml;
        out[(size_t)row*256 + col] = acc[fm][fn][r];
      }
}

// ---------------- fused angle head + periodic encoding + sampling metadata ----------
__global__ void k_aph1enc(const float* __restrict__ T, const float* __restrict__ b1,
    const float* __restrict__ w2, const float* __restrict__ b2,
    const float* __restrict__ freq,
    const float* __restrict__ ew1, const float* __restrict__ eb1,
    const float* __restrict__ lng, const float* __restrict__ lnb,
    const float* __restrict__ ew2, const float* __restrict__ eb2,
    short* __restrict__ gateA, int2* __restrict__ moff, float4* __restrict__ mw){
  const int KYi[9] = {-1,-1,-1,0,0,0,1,1,1};
  const int KXi[9] = {-1,0,1,-1,0,1,-1,0,1};
  __shared__ float sang[4];
  int lane = threadIdx.x & 63;
  int wid = threadIdx.x >> 6;
  int p = blockIdx.x*4 + wid;
  int hw = p & 4095;
  int h = hw >> 6, w = hw & 63;
  float acc = b1[lane];
  #pragma unroll
  for (int k = 0; k < 9; ++k){
    int y = h + KYi[k], x = w + KXi[k];
    if (y < 0 || y > 63 || x < 0 || x > 63) continue;
    acc += T[(size_t)(p + KYi[k]*64 + KXi[k])*640 + k*64 + lane];
  }
  float av = wsum64(fmaxf(acc, 0.f) * w2[lane]) + b2[0];
  if (lane == 0) sang[wid] = av;
  // ---- encode ----
  float an = av * (2.0f / PI_F);
  int f = lane & 31;
  float ph = an * freq[f] * ((float)f * (PI_F / 32.0f));
  float emb = (lane < 32) ? __sinf(ph) : __cosf(ph);
  float hh = eb1[lane];
  const float* w1r = ew1 + lane*64;
  #pragma unroll 8
  for (int i = 0; i < 64; ++i){
    float e = __shfl(emb, i, 64);
    hh = fmaf(e, w1r[i], hh);
  }
  float mu = wsum64(hh) * (1.0f/64.0f);
  float d = hh - mu;
  float var = wsum64(d*d) * (1.0f/64.0f);
  float hn = fmaf(d * rsqrtf(var + 1e-5f), lng[lane], lnb[lane]);
  float r = fmaxf(hn, 0.f);
  float o = eb2[lane];
  const float* w2r = ew2 + lane*64;
  #pragma unroll 8
  for (int i = 0; i < 64; ++i){
    float e = __shfl(r, i, 64);
    o = fmaf(e, w2r[i], o);
  }
  gateA[(size_t)p*320 + 256 + lane] = f2bf(o);
  // ---- sampling metadata (108 entries per block) ----
  __syncthreads();
  int tid = threadIdx.x;
  if (tid < 108){
    int lp = tid / 27;
    int j = tid - lp*27;
    int pp = blockIdx.x*4 + lp;
    int hyp = j / 9;
    int tap = j - hyp*9;
    float ky = (float)(tap/3 - 1), kx = (float)(tap - (tap/3)*3 - 1);
    float a = sang[lp] + ((float)hyp - 1.0f) * (PI_F / 12.0f);
    float sn = __sinf(a), cs = __cosf(a);
    int b2i = pp >> 12, hw2 = pp & 4095;
    float py = (float)(hw2 >> 6) + kx*sn + ky*cs;
    float px = (float)(hw2 & 63) + kx*cs - ky*sn;
    float y0f = floorf(py), x0f = floorf(px);
    float wy = py - y0f, wx = px - x0f;
    int y0 = (int)y0f, x0 = (int)x0f;
    bool vx0 = (unsigned)x0 < 64u, vx1 = (unsigned)(x0+1) < 64u;
    bool vy0 = (unsigned)y0 < 64u, vy1 = (unsigned)(y0+1) < 64u;
    int xb = vx0 ? x0 : (vx1 ? x0+1 : 0);
    float sx0 = vx0 ? 1.f-wx : (vx1 ? wx : 0.f);
    float sx1 = (vx0 && vx1) ? wx : 0.f;
    int ry0 = vy0 ? y0 : 0;
    int ry1 = vy1 ? y0+1 : 0;
    float vw0 = vy0 ? 1.f-wy : 0.f;
    float vw1 = vy1 ? wy : 0.f;
    int base = (b2i << 12);
    int mi = pp*27 + j;
    moff[mi] = make_int2(tap*4194304 + (base + ry0*64 + xb)*512,
                         tap*4194304 + (base + ry1*64 + xb)*512);
    mw[mi] = make_float4(vw0*sx0, vw0*sx1, vw1*sx0, vw1*sx1);
  }
}

// ---------------- bilinear gather on planar G: LDS meta, bounded unroll ----------
__global__ __launch_bounds__(256, 4) void k_sample(const short* __restrict__ G,
    const int2* __restrict__ moff, const float4* __restrict__ mw,
    const float* __restrict__ bias, short* __restrict__ cand){
  __shared__ int2 smo[216];
  __shared__ float4 smw[216];
  int id = blockIdx.x;                        // 1024 blocks
  int sw = (id & 7)*128 + (id >> 3);          // XCD band swizzle
  int tid = threadIdx.x;
  int pbase = sw*8;
  if (tid < 216){
    smo[tid] = moff[pbase*27 + tid];
    smw[tid] = mw[pbase*27 + tid];
  }
  __syncthreads();
  int lp = (tid >> 6)*2 + ((tid >> 5) & 1);   // local pixel 0..7
  int p = pbase + lp;
  int c8 = (tid & 31)*8;
  float av[3][8];
  {
    float4 b0 = *(const float4*)(bias + c8);
    float4 b1 = *(const float4*)(bias + c8 + 4);
    #pragma unroll
    for (int h2 = 0; h2 < 3; ++h2){
      av[h2][0]=b0.x; av[h2][1]=b0.y; av[h2][2]=b0.z; av[h2][3]=b0.w;
      av[h2][4]=b1.x; av[h2][5]=b1.y; av[h2][6]=b1.z; av[h2][7]=b1.w;
    }
  }
  #pragma unroll
  for (int hyp = 0; hyp < 3; ++hyp){
    #pragma unroll 3
    for (int tap = 0; tap < 9; ++tap){
      int idx = lp*27 + hyp*9 + tap;
      int2 o = smo[idx];
      float4 wv = smw[idx];
      const short* r0 = (const short*)((const char*)G + o.x) + c8;
      const short* r1 = (const short*)((const char*)G + o.y) + c8;
      short8 v00 = *(const short8*)r0;
      short8 v01 = *(const short8*)(r0 + 256);
      short8 v10 = *(const short8*)r1;
      short8 v11 = *(const short8*)(r1 + 256);
      #pragma unroll
      for (int e = 0; e < 8; ++e){
        float s = wv.x*bf2f(v00[e]) + wv.y*bf2f(v01[e]);
        s += wv.z*bf2f(v10[e]) + wv.w*bf2f(v11[e]);
        av[hyp][e] += s;
      }
    }
  }
  #pragma unroll
  for (int hyp = 0; hyp < 3; ++hyp){
    short8 o;
    #pragma unroll
    for (int e = 0; e < 8; ++e) o[e] = f2bf(av[hyp][e]);
    *(short8*)(cand + ((size_t)hyp*NPIX + p)*256 + c8) = o;
  }
}

// ---------------- sum 2 partials + bias -> t ; per-block GN partial stats ----------------
__global__ void k_sum3stat(const float* __restrict__ PG, const float* __restrict__ bias,
    float* __restrict__ t, float* __restrict__ spart){
  int p0 = blockIdx.x * 8;
  int c = threadIdx.x;
  float bb = bias[c];
  float s = 0.f, s2 = 0.f;
  #pragma unroll
  for (int pp = 0; pp < 8; ++pp){
    size_t idx = (size_t)(p0+pp)*256 + c;
    float v = PG[idx] + PG[idx + 2097152] + bb;
    t[idx] = v;
    s += v; s2 = fmaf(v, v, s2);
  }
  s  += __shfl_xor(s, 1, 64);  s  += __shfl_xor(s, 2, 64);  s  += __shfl_xor(s, 4, 64);
  s2 += __shfl_xor(s2, 1, 64); s2 += __shfl_xor(s2, 2, 64); s2 += __shfl_xor(s2, 4, 64);
  if ((c & 7) == 0){
    int b = p0 >> 12;
    int bg = b*32 + (c >> 3);
    int blk = blockIdx.x & 511;
    spart[(size_t)(bg*512 + blk)*2]     = s;
    spart[(size_t)(bg*512 + blk)*2 + 1] = s2;
  }
}

__global__ void k_gnfin(const float* __restrict__ spart, float* __restrict__ stat){
  int bg = blockIdx.x;
  const float* sp = spart + (size_t)bg*1024;
  float s = 0.f, s2 = 0.f;
  for (int i = threadIdx.x; i < 512; i += 256){
    s += sp[i*2]; s2 += sp[i*2+1];
  }
  s = wsum64(s); s2 = wsum64(s2);
  __shared__ float rs[4], rs2[4];
  int wid = threadIdx.x >> 6;
  if ((threadIdx.x & 63) == 0){ rs[wid] = s; rs2[wid] = s2; }
  __syncthreads();
  if (threadIdx.x == 0){
    float S = rs[0]+rs[1]+rs[2]+rs[3];
    float S2 = rs2[0]+rs2[1]+rs2[2]+rs2[3];
    float mean = S * (1.f/32768.f);
    float var = S2 * (1.f/32768.f) - mean*mean;
    stat[bg*2]   = mean;
    stat[bg*2+1] = rsqrtf(var + 1e-5f);
  }
}

// ---------------- GN+relu fused into final 1x1 projection, NCHW fp32 out ----------------
__global__ __launch_bounds__(256) void k_gnproj(const float* __restrict__ t,
    const float* __restrict__ stat, const float* __restrict__ gng,
    const float* __restrict__ gnb, const short* __restrict__ w2,
    const float* __restrict__ b2, float* __restrict__ out){
  __shared__ float cst[64*132];          // aliased: bf16 A tile (64x256) during GEMM
  __shared__ alignas(16) short sB[2][128*32];
  short* sA = (short*)cst;
  int tid = threadIdx.x;
  int m0 = blockIdx.x*64;
  int b = m0 >> 12;
  int srow = tid >> 2, sch = (tid & 3)*8;
  const short* Bgp = w2 + (size_t)(blockIdx.y*128 + srow)*256 + sch;
  short* sBd = &sB[0][srow*32 + sch];
  gl_lds(Bgp, sBd);
  gl_lds(Bgp + (size_t)64*256, sBd + 2048);
  // GN + relu -> bf16 A tile
  #pragma unroll 4
  for (int it = 0; it < 16; ++it){
    int c = it*256 + tid;
    int row = c >> 6;
    int col = (c & 63)*4;
    int g4 = col >> 3;
    float mean = stat[(b*32+g4)*2], rstd = stat[(b*32+g4)*2+1];
    float4 v = *(const float4*)(t + (size_t)(m0+row)*256 + col);
    float4 gg = *(const float4*)(gng + col);
    float4 bbv = *(const float4*)(gnb + col);
    short4_t o;
    o[0] = f2bf(fmaxf((v.x - mean)*rstd*gg.x + bbv.x, 0.f));
    o[1] = f2bf(fmaxf((v.y - mean)*rstd*gg.y + bbv.y, 0.f));
    o[2] = f2bf(fmaxf((v.z - mean)*rstd*gg.z + bbv.z, 0.f));
    o[3] = f2bf(fmaxf((v.w - mean)*rstd*gg.w + bbv.w, 0.f));
    *(short4_t*)&sA[row*256 + col] = o;
  }
  // GEMM: BM=64, BN=128: waves 2x2, WM=32, AF=2; A from sA, B dbuf
  int w = tid >> 6, l = tid & 63;
  int wr = w & 1, wc = w >> 1;
  int ml = l & 15, g = l >> 4;
  f32x4 acc[2][4];
  #pragma unroll
  for (int i = 0; i < 2; ++i)
    #pragma unroll
    for (int j = 0; j < 4; ++j) acc[i][j] = (f32x4){0.f,0.f,0.f,0.f};
  int buf = 0;
  for (int kt = 0; kt < 8; ++kt){
    __syncthreads();
    if (kt + 1 < 8){
      gl_lds(Bgp + (kt+1)*32, sBd + (buf^1)*4096);
      gl_lds(Bgp + (size_t)64*256 + (kt+1)*32, sBd + (buf^1)*4096 + 2048);
    }
    short8 af[2], bq[4];
    #pragma unroll
    for (int i = 0; i < 2; ++i)
      af[i] = *(const short8*)&sA[(wr*32 + i*16 + ml)*256 + kt*32 + g*8];
    #pragma unroll
    for (int j = 0; j < 4; ++j)
      bq[j] = *(const short8*)&sB[buf][(wc*64 + j*16 + ml)*32 + g*8];
    #pragma unroll
    for (int i = 0; i < 2; ++i)
      #pragma unroll
      for (int j = 0; j < 4; ++j)
        acc[i][j] = __builtin_amdgcn_mfma_f32_16x16x32_bf16(af[i], bq[j], acc[i][j], 0, 0, 0);
    buf ^= 1;
  }
  __syncthreads();   // sA dead; reuse as cst
  #pragma unroll
  for (int fm = 0; fm < 2; ++fm)
    #pragma unroll
    for (int fn = 0; fn < 4; ++fn)
      #pragma unroll
      for (int r = 0; r < 4; ++r){
        int cl = wc*64 + fn*16 + ml;
        cst[(wr*32 + fm*16 + g*4 + r)*132 + cl] = acc[fm][fn][r] + b2[blockIdx.y*128 + cl];
      }
  __syncthreads();
  int hw0 = m0 & 4095;
  int o = tid >> 1, seg = (tid & 1)*32;
  float* op = out + (((size_t)(b*256 + blockIdx.y*128 + o)) << 12) + hw0 + seg;
  #pragma unroll
  for (int i = 0; i < 32; i += 4){
    float4 vv = {cst[(seg+i)*132+o], cst[(seg+i+1)*132+o],
                 cst[(seg+i+2)*132+o], cst[(seg+i+3)*132+o]};
    *(float4*)(op + i) = vv;
  }
}

// ---------------- launch ----------------
extern "C" void kernel_launch(void* const* d_in, const int* in_sizes, int n_in,
                              void* d_out, int out_size, void* d_ws, size_t ws_size,
                              hipStream_t stream){
  (void)in_sizes; (void)n_in; (void)out_size; (void)ws_size;
  const float* features   = (const float*)d_in[0];
  const float* ap_w1      = (const float*)d_in[1];
  const float* ap_b1      = (const float*)d_in[2];
  const float* ap_w2      = (const float*)d_in[3];
  const float* ap_b2      = (const float*)d_in[4];
  const float* freq       = (const float*)d_in[5];
  const float* ae_w1      = (const float*)d_in[6];
  const float* ae_b1      = (const float*)d_in[7];
  const float* ae_ln_g    = (const float*)d_in[8];
  const float* ae_ln_b    = (const float*)d_in[9];
  const float* ae_w2      = (const float*)d_in[10];
  const float* ae_b2      = (const float*)d_in[11];
  const float* dc_w       = (const float*)d_in[12];
  const float* dc_b       = (const float*)d_in[13];
  const float* attn_in_w  = (const float*)d_in[14];
  const float* attn_in_b  = (const float*)d_in[15];
  const float* attn_out_w = (const float*)d_in[16];
  const float* attn_out_b = (const float*)d_in[17];
  const float* ja_w1      = (const float*)d_in[18];
  const float* ja_b1      = (const float*)d_in[19];
  const float* ja_w2      = (const float*)d_in[20];
  const float* ja_b2      = (const float*)d_in[21];
  const float* op_w1      = (const float*)d_in[22];
  const float* op_b1      = (const float*)d_in[23];
  const float* gn_g       = (const float*)d_in[24];
  const float* gn_b       = (const float*)d_in[25];
  const float* op_w2      = (const float*)d_in[26];
  const float* op_b2      = (const float*)d_in[27];

  char* base = (char*)d_ws;
  #define ALLOC(ty, name, elems) ty* name = (ty*)base; base += (size_t)(elems)*sizeof(ty);
  ALLOC(short, Bdc,     2304*256)
  ALLOC(short, B2op,    256*2304)
  ALLOC(short, B3ap,    640*512)
  ALLOC(short, inw_bf,  768*256)
  ALLOC(short, wot_bf,  256*256)
  ALLOC(short, jw1_bf,  256*320)
  ALLOC(short, jw2_bf,  256*256)
  ALLOC(short, wop2_bf, 256*256)
  ALLOC(short, A3,      8192*512)    // [hi|lo] per pixel; G reads hi half (lda=512)
  ALLOC(short, Gbuf,    24576*768)   // serves: planar G -> KV/Q -> PG(fp32 x2)
  ALLOC(short, gguard,  256)         // OOB-wrap guard for k_sample edge reads (512B)
  ALLOC(float, T_ap,    8192*640)
  ALLOC(short, cand_bf, 3*8192*256)
  ALLOC(short, gateA,   8192*320)
  ALLOC(short, hid_bf,  8192*256)
  ALLOC(short, enh_pad, 2*4356*256)  // (B,66,66,256); ring zeroed each call, interior rewritten
  ALLOC(float, tbuf,    8192*256)
  ALLOC(float, gstat,   128)
  ALLOC(float, spart,   65536)
  ALLOC(int,   moffb,   2*NPIX*27)
  ALLOC(float, mwb,     4*NPIX*27)
  #undef ALLOC
  (void)gguard;
  short* KVbuf = Gbuf;                      // 24576*512 bf16
  short* Qbuf  = Gbuf + (size_t)24576*512;  // 8192*256 bf16
  float* PG    = (float*)Gbuf;              // 2 x 8192*256 fp32 partials
  int2*  moff  = (int2*)moffb;
  float4* mwv  = (float4*)mwb;

  k_prepall<<<4258, 256, 0, stream>>>(dc_w, op_w1, ap_w1, features,
      attn_in_w, attn_out_w, ja_w1, ja_w2, op_w2,
      enh_pad, Bdc, B2op, B3ap, A3,
      inw_bf, wot_bf, jw1_bf, jw2_bf, wop2_bf);

  // G (tap-planar, K=256) + T_ap (K=512) in one dispatch
  k_mainA<<<dim3(64,23), 256, 0, stream>>>(A3, Bdc, B3ap, Gbuf, T_ap);
  k_aph1enc<<<2048, 256, 0, stream>>>(T_ap, ap_b1, ap_w2, ap_b2, freq,
                                      ae_w1, ae_b1, ae_ln_g, ae_ln_b, ae_w2, ae_b2,
                                      gateA, moff, mwv);
  k_sample<<<1024, 256, 0, stream>>>(Gbuf, moff, mwv, dc_b, cand_bf);
  // Q + KV projections in one dispatch
  k_qkv<<<dim3(192,5), 256, 0, stream>>>(cand_bf, inw_bf, attn_in_b, KVbuf, Qbuf);
  // attention + output projection fused -> gateA cols 0..255
  k_attnproj<<<dim3(128,4), 256, 0, stream>>>(Qbuf, KVbuf, wot_bf, attn_out_b, gateA);
  // hid = relu(gateA x ja_w1^T + b1)
  k_gemml<2,64,64><<<dim3(128,4), 256, 0, stream>>>(gateA, jw1_bf, hid_bf, ja_b1, nullptr, 320, 256);
  // enh = fused * (1 + sigmoid(hid x ja_w2^T + b2)) -> padded NHWC
  k_gemml<6,64,64><<<dim3(128,4), 256, 0, stream>>>(hid_bf, jw2_bf, enh_pad, ja_b2, gateA, 256, 256);
  // conv3x3(enh_pad, op_w1): split-K=2 partials then fused sum+bias+GN-stats
  k_igconv<<<dim3(128,2,2), 256, 0, stream>>>(enh_pad, B2op, PG);
  k_sum3stat<<<1024, 256, 0, stream>>>(PG, op_b1, tbuf, spart);
  k_gnfin<<<64, 256, 0, stream>>>(spart, gstat);
  // GN + relu + out-projection fused, NCHW fp32
  k_gnproj<<<dim3(128,2), 256, 0, stream>>>(tbuf, gstat, gn_g, gn_b, wop2_bf, op_b2,
                                            (float*)d_out);
}

// Round 15
// 185.992 us; speedup vs baseline: 1.0113x; 1.0113x over previous
//
#include <hip/hip_runtime.h>

#define PI_F 3.14159265358979323846f
#define HWSZ 4096   // H*W
#define NPIX 8192   // B*H*W

typedef __attribute__((ext_vector_type(8))) short short8;
typedef __attribute__((ext_vector_type(4))) short short4_t;
typedef __attribute__((ext_vector_type(4))) float f32x4;

__device__ __forceinline__ short f2bf(float x){
  unsigned u = __float_as_uint(x);
  unsigned r = (u + 0x7FFFu + ((u >> 16) & 1u)) >> 16;
  return (short)r;
}
__device__ __forceinline__ float bf2f(short v){
  return __uint_as_float(((unsigned)(unsigned short)v) << 16);
}

__device__ __forceinline__ float wsum64(float v){
  #pragma unroll
  for (int m = 32; m >= 1; m >>= 1) v += __shfl_xor(v, m, 64);
  return v;
}
__device__ __forceinline__ float wsum8(float v){
  v += __shfl_xor(v, 1, 64);
  v += __shfl_xor(v, 2, 64);
  v += __shfl_xor(v, 4, 64);
  return v;
}

// async global->LDS, 16B per lane.
__device__ __forceinline__ void gl_lds(const short* g, short* s){
  __builtin_amdgcn_global_load_lds(
      (const __attribute__((address_space(1))) unsigned int*)g,
      (__attribute__((address_space(3))) unsigned int*)s, 16, 0, 0);
}

// ---------------- merged prep + layout kernel (sectioned by blockIdx.x) ----------------
// sec0 [0,130): zero enh_pad RING only ; sec1 [130,386): dc_w->Bdc ;
// sec2 [386,642): op_w1->B2op ; sec3 [642,1282): apw3 ; sec4 [1282,2210): cast x2 ;
// sec5 [2210,4258): nchw_split
__global__ void k_prepall(const float* __restrict__ dc_w, const float* __restrict__ op_w1,
    const float* __restrict__ ap_w1, const float* __restrict__ features,
    const float* __restrict__ s0, const float* __restrict__ s1,
    const float* __restrict__ s2, const float* __restrict__ s3, const float* __restrict__ s4,
    short* __restrict__ enh_pad, short* __restrict__ Bdc, short* __restrict__ B2op,
    short* __restrict__ B3, short* __restrict__ A3,
    short* __restrict__ d0, short* __restrict__ d1,
    short* __restrict__ d2, short* __restrict__ d3, short* __restrict__ d4){
  __shared__ short tile[2304];
  __shared__ float ft[32][33];
  int bx = blockIdx.x, tid = threadIdx.x;
  if (bx < 130){
    int i = bx*256 + tid;           // short4 index over ring pixels [0, 33280)
    if (i < 33280){
      int px = i >> 6;              // 0..519
      int c4 = (i & 63) * 4;
      int b = px >= 260 ? 1 : 0;
      int r = px - b*260;
      int row, col;
      if (r < 66){ row = 0; col = r; }
      else if (r < 132){ row = 65; col = r - 66; }
      else { int rr = r - 132; row = (rr >> 1) + 1; col = (rr & 1)*65; }
      int pp = b*4356 + row*66 + col;
      *(short4_t*)(enh_pad + (size_t)pp*256 + c4) = (short4_t){0,0,0,0};
    }
  } else if (bx < 386){
    int o = bx - 130;
    const float* wo = dc_w + (size_t)o*2304;
    for (int i = tid; i < 2304; i += 256){
      int c = i / 9, k = i - c*9;
      tile[k*256 + c] = f2bf(wo[i]);
    }
    __syncthreads();
    for (int i = tid; i < 2304; i += 256){
      int k = i >> 8, c = i & 255;
      Bdc[((size_t)(k*256 + o))*256 + c] = tile[i];
    }
  } else if (bx < 642){
    int o = bx - 386;
    const float* wo = op_w1 + (size_t)o*2304;
    for (int i = tid; i < 2304; i += 256){
      int c = i / 9, k = i - c*9;
      tile[k*256 + c] = f2bf(wo[i]);
    }
    __syncthreads();
    short* out = B2op + (size_t)o*2304;
    for (int i = tid; i < 2304; i += 256) out[i] = tile[i];
  } else if (bx < 1282){
    int n = bx - 642, c = tid;
    short hi = 0;
    if (n < 576){
      int o = n & 63, k = n >> 6;
      hi = f2bf(ap_w1[((size_t)o*256 + c)*9 + k]);
    }
    B3[(size_t)n*512 + c] = hi;
    B3[(size_t)n*512 + 256 + c] = hi;
  } else if (bx < 2210){
    int i = (bx - 1282)*512 + tid;
    #pragma unroll
    for (int rep = 0; rep < 2; ++rep){
      if (i < 196608) d0[i] = f2bf(s0[i]);
      else if (i < 262144) d1[i-196608] = f2bf(s1[i-196608]);
      else if (i < 344064) d2[i-262144] = f2bf(s2[i-262144]);
      else if (i < 409600) d3[i-344064] = f2bf(s3[i-344064]);
      else if (i < 475136) d4[i-409600] = f2bf(s4[i-409600]);
      i += 256;
    }
  } else {
    int bid = bx - 2210;
    int z = bid >> 10;
    int rem = bid & 1023;
    int p0 = (rem & 127)*32, c0 = (rem >> 7)*32;
    int tx = tid & 31, ty = tid >> 5;
    #pragma unroll
    for (int i = ty; i < 32; i += 8)
      ft[i][tx] = features[((size_t)z*256 + c0 + i)*HWSZ + p0 + tx];
    __syncthreads();
    #pragma unroll
    for (int i = ty; i < 32; i += 8){
      float x = ft[tx][i];
      short hi = f2bf(x);
      short lo = f2bf(x - bf2f(hi));
      size_t p = (size_t)z*HWSZ + p0 + i;
      A3[p*512 + c0 + tx] = hi;
      A3[p*512 + 256 + c0 + tx] = lo;
    }
  }
}

// ---------------- merged front-end GEMM: G (tap-planar) + T_ap, one dispatch ----------
// grid (64, 23). y<18: G = A3.hi x Bdc^T (K=256) -> planar [9][8192][256] bf16
//                y>=18: T = A3 x B3^T (K=512) -> fp32 (8192,640)
__global__ __launch_bounds__(256) void k_mainA(const short* __restrict__ A3,
    const short* __restrict__ Bdc, const short* __restrict__ B3,
    short* __restrict__ G, float* __restrict__ T){
  __shared__ alignas(16) short sA[2][128*32];
  __shared__ alignas(16) short sB[2][128*32];
  bool isG = blockIdx.y < 18;
  const short* B; int K, ldb, n0;
  if (isG){ B = Bdc; K = 256; ldb = 256; n0 = blockIdx.y*128; }
  else    { B = B3;  K = 512; ldb = 512; n0 = ((int)blockIdx.y - 18)*128; }
  int tid = threadIdx.x;
  int w = tid >> 6, l = tid & 63;
  int wc = w & 1, wr = w >> 1;
  int ml = l & 15, g = l >> 4;
  int srow = tid >> 2;
  int sch = (tid & 3)*8;
  int m0 = blockIdx.x*128;
  const short* Agp = A3 + (size_t)(m0 + srow)*512 + sch;
  const short* Bgp = B + (size_t)(n0 + srow)*ldb + sch;
  short* sAd = &sA[0][srow*32 + sch];
  short* sBd = &sB[0][srow*32 + sch];
  f32x4 acc[4][4];
  #pragma unroll
  for (int i = 0; i < 4; ++i)
    #pragma unroll
    for (int j = 0; j < 4; ++j) acc[i][j] = (f32x4){0.f,0.f,0.f,0.f};
  #define STG(bf, kt) { \
    gl_lds(Agp + (kt)*32, sAd + (bf)*4096); \
    gl_lds(Agp + (size_t)64*512 + (kt)*32, sAd + (bf)*4096 + 2048); \
    gl_lds(Bgp + (kt)*32, sBd + (bf)*4096); \
    gl_lds(Bgp + (size_t)64*ldb + (kt)*32, sBd + (bf)*4096 + 2048); \
  }
  int nk = K >> 5;
  STG(0, 0)
  int buf = 0;
  for (int kt = 0; kt < nk; ++kt){
    __syncthreads();
    if (kt + 1 < nk){ STG(buf^1, kt+1) }
    short8 af[4], bq[4];
    #pragma unroll
    for (int i = 0; i < 4; ++i)
      af[i] = *(const short8*)&sA[buf][(wr*64 + i*16 + ml)*32 + g*8];
    #pragma unroll
    for (int j = 0; j < 4; ++j)
      bq[j] = *(const short8*)&sB[buf][(wc*64 + j*16 + ml)*32 + g*8];
    #pragma unroll
    for (int i = 0; i < 4; ++i)
      #pragma unroll
      for (int j = 0; j < 4; ++j)
        acc[i][j] = __builtin_amdgcn_mfma_f32_16x16x32_bf16(af[i], bq[j], acc[i][j], 0, 0, 0);
    buf ^= 1;
  }
  #undef STG
  int m0w = m0 + wr*64;
  int n0w = n0 + wc*64;
  #pragma unroll
  for (int fm = 0; fm < 4; ++fm)
    #pragma unroll
    for (int fn = 0; fn < 4; ++fn)
      #pragma unroll
      for (int r = 0; r < 4; ++r){
        int row = m0w + fm*16 + g*4 + r;
        int col = n0w + fn*16 + ml;
        float v = acc[fm][fn][r];
        if (isG)
          G[(size_t)(col>>8)*2097152 + (size_t)row*256 + (col&255)] = f2bf(v);
        else
          T[(size_t)row*640 + col] = v;
      }
}

// ---------------- LDS-staged bf16 TN GEMM template (small-N chain) ----------------
// EPI: 2 bf16 relu+bias; 6 gate->padded NHWC
template<int EPI, int BM, int BN = 128>
__global__ __launch_bounds__(256) void k_gemml(const short* __restrict__ A,
    const short* __restrict__ B, void* __restrict__ Cv,
    const float* __restrict__ bias, const short* __restrict__ aux,
    int K, int ldc){
  constexpr int NWC = BN/64;
  constexpr int NWR = 4/NWC;
  constexpr int WM = BM/NWR;
  constexpr int AF = WM/16;
  __shared__ alignas(16) short sA[2][BM*32];
  __shared__ alignas(16) short sB[2][BN*32];
  int tid = threadIdx.x;
  int w = tid >> 6, l = tid & 63;
  int wc = w % NWC, wr = w / NWC;
  int ml = l & 15, g = l >> 4;
  int srow = tid >> 2;
  int sch = (tid & 3)*8;
  int m0 = blockIdx.x*BM, n0 = blockIdx.y*BN;
  const short* Agp = A + (size_t)(m0 + srow)*K + sch;
  const short* Bgp = B + (size_t)(n0 + srow)*K + sch;
  short* sAd = &sA[0][srow*32 + sch];
  short* sBd = &sB[0][srow*32 + sch];
  f32x4 acc[AF][4];
  #pragma unroll
  for (int i = 0; i < AF; ++i)
    #pragma unroll
    for (int j = 0; j < 4; ++j) acc[i][j] = (f32x4){0.f,0.f,0.f,0.f};

  #define STAGE(bf, kt) { \
    _Pragma("unroll") \
    for (int c = 0; c < BM/64; ++c) \
      gl_lds(Agp + (size_t)(c*64)*K + (kt)*32, sAd + (bf)*BM*32 + c*2048); \
    _Pragma("unroll") \
    for (int c = 0; c < BN/64; ++c) \
      gl_lds(Bgp + (size_t)(c*64)*K + (kt)*32, sBd + (bf)*BN*32 + c*2048); \
  }
  int nk = K >> 5;
  STAGE(0, 0)
  int buf = 0;
  for (int kt = 0; kt < nk; ++kt){
    __syncthreads();
    if (kt + 1 < nk){ STAGE(buf^1, kt+1) }
    short8 af[AF], bq[4];
    #pragma unroll
    for (int i = 0; i < AF; ++i)
      af[i] = *(const short8*)&sA[buf][(wr*WM + i*16 + ml)*32 + g*8];
    #pragma unroll
    for (int j = 0; j < 4; ++j)
      bq[j] = *(const short8*)&sB[buf][(wc*64 + j*16 + ml)*32 + g*8];
    #pragma unroll
    for (int i = 0; i < AF; ++i)
      #pragma unroll
      for (int j = 0; j < 4; ++j)
        acc[i][j] = __builtin_amdgcn_mfma_f32_16x16x32_bf16(af[i], bq[j], acc[i][j], 0, 0, 0);
    buf ^= 1;
  }
  #undef STAGE

  int m0w = m0 + wr*WM;
  int n0w = n0 + wc*64;
  #pragma unroll
  for (int fm = 0; fm < AF; ++fm)
    #pragma unroll
    for (int fn = 0; fn < 4; ++fn)
      #pragma unroll
      for (int r = 0; r < 4; ++r){
        int row = m0w + fm*16 + g*4 + r;
        int col = n0w + fn*16 + ml;
        float v = acc[fm][fn][r];
        if constexpr (EPI == 2){
          ((short*)Cv)[(size_t)row*ldc + col] = f2bf(fmaxf(v + bias[col], 0.f));
        } else if constexpr (EPI == 6){
          float f = bf2f(aux[(size_t)row*320 + col]);
          float s = 1.f/(1.f + __expf(-(v + bias[col])));
          int b = row >> 12, hw = row & 4095;
          int pi = b*4356 + ((hw>>6)+1)*66 + (hw&63) + 1;
          ((short*)Cv)[(size_t)pi*256 + col] = f2bf(f * (1.f + s));
        }
      }
}

// ---------------- merged Q + KV projection GEMM (one dispatch) ----------------
__global__ __launch_bounds__(256) void k_qkv(const short* __restrict__ cand,
    const short* __restrict__ inw, const float* __restrict__ inb,
    short* __restrict__ KV, short* __restrict__ Qb){
  const short* A; const short* B; short* C; const float* bias; int ldc, m0, n0;
  if (blockIdx.y < 4){
    A = cand; B = inw + (size_t)256*256; C = KV; bias = inb + 256; ldc = 512;
    m0 = blockIdx.x*128; n0 = blockIdx.y*128;
  } else {
    if (blockIdx.x >= 128) return;
    A = cand + (size_t)NPIX*256; B = inw; C = Qb; bias = inb; ldc = 256;
    m0 = (blockIdx.x >> 1)*128; n0 = (blockIdx.x & 1)*128;
  }
  __shared__ alignas(16) short sA[2][128*32];
  __shared__ alignas(16) short sB[2][128*32];
  int tid = threadIdx.x;
  int w = tid >> 6, l = tid & 63;
  int wc = w & 1, wr = w >> 1;
  int ml = l & 15, g = l >> 4;
  int srow = tid >> 2;
  int sch = (tid & 3)*8;
  const short* Agp = A + (size_t)(m0 + srow)*256 + sch;
  const short* Bgp = B + (size_t)(n0 + srow)*256 + sch;
  short* sAd = &sA[0][srow*32 + sch];
  short* sBd = &sB[0][srow*32 + sch];
  f32x4 acc[4][4];
  #pragma unroll
  for (int i = 0; i < 4; ++i)
    #pragma unroll
    for (int j = 0; j < 4; ++j) acc[i][j] = (f32x4){0.f,0.f,0.f,0.f};
  #define STG2(bf, kt) { \
    gl_lds(Agp + (kt)*32, sAd + (bf)*4096); \
    gl_lds(Agp + (size_t)64*256 + (kt)*32, sAd + (bf)*4096 + 2048); \
    gl_lds(Bgp + (kt)*32, sBd + (bf)*4096); \
    gl_lds(Bgp + (size_t)64*256 + (kt)*32, sBd + (bf)*4096 + 2048); \
  }
  STG2(0, 0)
  int buf = 0;
  for (int kt = 0; kt < 8; ++kt){
    __syncthreads();
    if (kt + 1 < 8){ STG2(buf^1, kt+1) }
    short8 af[4], bq[4];
    #pragma unroll
    for (int i = 0; i < 4; ++i)
      af[i] = *(const short8*)&sA[buf][(wr*64 + i*16 + ml)*32 + g*8];
    #pragma unroll
    for (int j = 0; j < 4; ++j)
      bq[j] = *(const short8*)&sB[buf][(wc*64 + j*16 + ml)*32 + g*8];
    #pragma unroll
    for (int i = 0; i < 4; ++i)
      #pragma unroll
      for (int j = 0; j < 4; ++j)
        acc[i][j] = __builtin_amdgcn_mfma_f32_16x16x32_bf16(af[i], bq[j], acc[i][j], 0, 0, 0);
    buf ^= 1;
  }
  #undef STG2
  int m0w = m0 + wr*64;
  int n0w = n0 + wc*64;
  #pragma unroll
  for (int fm = 0; fm < 4; ++fm)
    #pragma unroll
    for (int fn = 0; fn < 4; ++fn)
      #pragma unroll
      for (int r = 0; r < 4; ++r){
        int row = m0w + fm*16 + g*4 + r;
        int col = n0w + fn*16 + ml;
        C[(size_t)row*ldc + col] = f2bf(acc[fm][fn][r] + bias[col]);
      }
}

// ---------------- attention core fused with output projection ----------------
__global__ __launch_bounds__(256) void k_attnproj(const short* __restrict__ Qb,
    const short* __restrict__ KVb, const short* __restrict__ wot,
    const float* __restrict__ outb, short* __restrict__ gateA){
  __shared__ alignas(16) short sO[64*256];
  __shared__ alignas(16) short sB[2][64*32];
  int tid = threadIdx.x;
  int m0 = blockIdx.x*64, n0 = blockIdx.y*64;
  int srow = tid >> 2, sch = (tid & 3)*8;
  const short* Bgp = wot + (size_t)(n0 + srow)*256 + sch;
  short* sBd = &sB[0][srow*32 + sch];
  gl_lds(Bgp, sBd);                 // first B stage overlaps attn compute
  int lane = tid & 63;
  int sub = tid >> 6;
  const float sc = 0.17677669529663688f; // 1/sqrt(32)
  #pragma unroll 2
  for (int it = 0; it < 16; ++it){
    int lp = it*4 + sub;
    int p = m0 + lp;
    float q[4];
    { short4_t t = *(const short4_t*)(Qb + (size_t)p*256 + lane*4);
      #pragma unroll
      for (int j = 0; j < 4; ++j) q[j] = bf2f(t[j]); }
    float kv[3][2][4];
    #pragma unroll
    for (int i = 0; i < 3; ++i){
      const short* rp = KVb + (size_t)(i*NPIX + p)*512 + lane*4;
      short4_t kt = *(const short4_t*)rp;
      short4_t vt = *(const short4_t*)(rp + 256);
      #pragma unroll
      for (int j = 0; j < 4; ++j){ kv[i][0][j] = bf2f(kt[j]); kv[i][1][j] = bf2f(vt[j]); }
    }
    float s[3];
    #pragma unroll
    for (int i = 0; i < 3; ++i){
      float d = 0.f;
      #pragma unroll
      for (int j = 0; j < 4; ++j) d = fmaf(q[j], kv[i][0][j], d);
      s[i] = wsum8(d) * sc;
    }
    float m = fmaxf(s[0], fmaxf(s[1], s[2]));
    float e0 = __expf(s[0]-m), e1 = __expf(s[1]-m), e2 = __expf(s[2]-m);
    float inv = 1.f/(e0+e1+e2);
    short4_t ot;
    #pragma unroll
    for (int j = 0; j < 4; ++j)
      ot[j] = f2bf((e0*kv[0][1][j] + e1*kv[1][1][j] + e2*kv[2][1][j]) * inv);
    *(short4_t*)&sO[lp*256 + lane*4] = ot;
  }
  // GEMM: A = sO (64x256), B = wot rows [n0,n0+64), 8 K-steps
  int w = sub, ml = lane & 15, g = lane >> 4;
  f32x4 acc[4];
  #pragma unroll
  for (int j = 0; j < 4; ++j) acc[j] = (f32x4){0.f,0.f,0.f,0.f};
  int buf = 0;
  for (int kt = 0; kt < 8; ++kt){
    __syncthreads();
    if (kt + 1 < 8) gl_lds(Bgp + (kt+1)*32, sBd + (buf^1)*2048);
    short8 af = *(const short8*)&sO[(w*16 + ml)*256 + kt*32 + g*8];
    short8 bq[4];
    #pragma unroll
    for (int j = 0; j < 4; ++j)
      bq[j] = *(const short8*)&sB[buf][(j*16 + ml)*32 + g*8];
    #pragma unroll
    for (int j = 0; j < 4; ++j)
      acc[j] = __builtin_amdgcn_mfma_f32_16x16x32_bf16(af, bq[j], acc[j], 0, 0, 0);
    buf ^= 1;
  }
  int m0w = m0 + w*16;
  #pragma unroll
  for (int fn = 0; fn < 4; ++fn)
    #pragma unroll
    for (int r = 0; r < 4; ++r){
      int row = m0w + g*4 + r;
      int col = n0 + fn*16 + ml;
      gateA[(size_t)row*320 + col] = f2bf(acc[fn][r] + outb[col]);
    }
}

// ---------------- implicit-GEMM 3x3 conv, LDS-staged, split-K=3 by tap group ----------
__global__ __launch_bounds__(256) void k_igconv(const short* __restrict__ Xpad,
    const short* __restrict__ B2, float* __restrict__ PG){
  __shared__ alignas(16) short sA[2][64*32];
  __shared__ alignas(16) short sB[2][128*32];
  int zg = blockIdx.z;
  int tid = threadIdx.x;
  int w = tid >> 6, l = tid & 63;
  int wr = w & 1, wc = w >> 1;
  int ml = l & 15, g = l >> 4;
  int srow = tid >> 2;
  int sch = (tid & 3)*8;
  int m0 = blockIdx.x*64, n0 = blockIdx.y*128;
  int b = blockIdx.x >> 6, imgrow = blockIdx.x & 63;
  int qbase = b*4356 + (imgrow+1)*66 + srow + 1;
  const short* Bgp = B2 + (size_t)(n0 + srow)*2304 + zg*768 + sch;
  short* sAd = &sA[0][srow*32 + sch];
  short* sBd = &sB[0][srow*32 + sch];
  int toff[3];
  #pragma unroll
  for (int i = 0; i < 3; ++i){
    int t = zg*3 + i;
    toff[i] = (t/3 - 1)*66 + (t%3) - 1;
  }
  f32x4 acc[2][4];
  #pragma unroll
  for (int i = 0; i < 2; ++i)
    #pragma unroll
    for (int j = 0; j < 4; ++j) acc[i][j] = (f32x4){0.f,0.f,0.f,0.f};

  #define STG(bf, kt) { \
    int tap = (kt) >> 3, cofs = ((kt) & 7)*32; \
    gl_lds(Xpad + (size_t)(qbase + toff[tap])*256 + cofs + sch, sAd + (bf)*2048); \
    gl_lds(Bgp + (kt)*32, sBd + (bf)*4096); \
    gl_lds(Bgp + (size_t)64*2304 + (kt)*32, sBd + (bf)*4096 + 2048); \
  }
  STG(0, 0)
  int buf = 0;
  for (int kt = 0; kt < 24; ++kt){
    __syncthreads();
    if (kt < 23){ STG(buf^1, kt+1) }
    short8 af[2], bq[4];
    #pragma unroll
    for (int i = 0; i < 2; ++i)
      af[i] = *(const short8*)&sA[buf][(wr*32 + i*16 + ml)*32 + g*8];
    #pragma unroll
    for (int j = 0; j < 4; ++j)
      bq[j] = *(const short8*)&sB[buf][(wc*64 + j*16 + ml)*32 + g*8];
    #pragma unroll
    for (int i = 0; i < 2; ++i)
      #pragma unroll
      for (int j = 0; j < 4; ++j)
        acc[i][j] = __builtin_amdgcn_mfma_f32_16x16x32_bf16(af[i], bq[j], acc[i][j], 0, 0, 0);
    buf ^= 1;
  }
  #undef STG

  float* out = PG + (size_t)zg*2097152;
  int m0w = m0 + wr*32;
  int n0w = n0 + wc*64;
  #pragma unroll
  for (int fm = 0; fm < 2; ++fm)
    #pragma unroll
    for (int fn = 0; fn < 4; ++fn)
      #pragma unroll
      for (int r = 0; r < 4; ++r){
        int row = m0w + fm*16 + g*4 + r;
        int col = n0w + fn*16 + ml;
        out[(size_t)row*256 + col] = acc[fm][fn][r];
      }
}

// ---------------- fused angle head + periodic encoding + sampling metadata ----------
__global__ void k_aph1enc(const float* __restrict__ T, const float* __restrict__ b1,
    const float* __restrict__ w2, const float* __restrict__ b2,
    const float* __restrict__ freq,
    const float* __restrict__ ew1, const float* __restrict__ eb1,
    const float* __restrict__ lng, const float* __restrict__ lnb,
    const float* __restrict__ ew2, const float* __restrict__ eb2,
    short* __restrict__ gateA, int2* __restrict__ moff, float4* __restrict__ mw){
  const int KYi[9] = {-1,-1,-1,0,0,0,1,1,1};
  const int KXi[9] = {-1,0,1,-1,0,1,-1,0,1};
  __shared__ float sang[4];
  int lane = threadIdx.x & 63;
  int wid = threadIdx.x >> 6;
  int p = blockIdx.x*4 + wid;
  int hw = p & 4095;
  int h = hw >> 6, w = hw & 63;
  float acc = b1[lane];
  #pragma unroll
  for (int k = 0; k < 9; ++k){
    int y = h + KYi[k], x = w + KXi[k];
    if (y < 0 || y > 63 || x < 0 || x > 63) continue;
    acc += T[(size_t)(p + KYi[k]*64 + KXi[k])*640 + k*64 + lane];
  }
  float av = wsum64(fmaxf(acc, 0.f) * w2[lane]) + b2[0];
  if (lane == 0) sang[wid] = av;
  // ---- encode ----
  float an = av * (2.0f / PI_F);
  int f = lane & 31;
  float ph = an * freq[f] * ((float)f * (PI_F / 32.0f));
  float emb = (lane < 32) ? __sinf(ph) : __cosf(ph);
  float hh = eb1[lane];
  const float* w1r = ew1 + lane*64;
  #pragma unroll 8
  for (int i = 0; i < 64; ++i){
    float e = __shfl(emb, i, 64);
    hh = fmaf(e, w1r[i], hh);
  }
  float mu = wsum64(hh) * (1.0f/64.0f);
  float d = hh - mu;
  float var = wsum64(d*d) * (1.0f/64.0f);
  float hn = fmaf(d * rsqrtf(var + 1e-5f), lng[lane], lnb[lane]);
  float r = fmaxf(hn, 0.f);
  float o = eb2[lane];
  const float* w2r = ew2 + lane*64;
  #pragma unroll 8
  for (int i = 0; i < 64; ++i){
    float e = __shfl(r, i, 64);
    o = fmaf(e, w2r[i], o);
  }
  gateA[(size_t)p*320 + 256 + lane] = f2bf(o);
  // ---- sampling metadata (108 entries per block) ----
  __syncthreads();
  int tid = threadIdx.x;
  if (tid < 108){
    int lp = tid / 27;
    int j = tid - lp*27;
    int pp = blockIdx.x*4 + lp;
    int hyp = j / 9;
    int tap = j - hyp*9;
    float ky = (float)(tap/3 - 1), kx = (float)(tap - (tap/3)*3 - 1);
    float a = sang[lp] + ((float)hyp - 1.0f) * (PI_F / 12.0f);
    float sn = __sinf(a), cs = __cosf(a);
    int b2i = pp >> 12, hw2 = pp & 4095;
    float py = (float)(hw2 >> 6) + kx*sn + ky*cs;
    float px = (float)(hw2 & 63) + kx*cs - ky*sn;
    float y0f = floorf(py), x0f = floorf(px);
    float wy = py - y0f, wx = px - x0f;
    int y0 = (int)y0f, x0 = (int)x0f;
    bool vx0 = (unsigned)x0 < 64u, vx1 = (unsigned)(x0+1) < 64u;
    bool vy0 = (unsigned)y0 < 64u, vy1 = (unsigned)(y0+1) < 64u;
    int xb = vx0 ? x0 : (vx1 ? x0+1 : 0);
    float sx0 = vx0 ? 1.f-wx : (vx1 ? wx : 0.f);
    float sx1 = (vx0 && vx1) ? wx : 0.f;
    int ry0 = vy0 ? y0 : 0;
    int ry1 = vy1 ? y0+1 : 0;
    float vw0 = vy0 ? 1.f-wy : 0.f;
    float vw1 = vy1 ? wy : 0.f;
    int base = (b2i << 12);
    int mi = pp*27 + j;
    moff[mi] = make_int2(tap*4194304 + (base + ry0*64 + xb)*512,
                         tap*4194304 + (base + ry1*64 + xb)*512);
    mw[mi] = make_float4(vw0*sx0, vw0*sx1, vw1*sx0, vw1*sx1);
  }
}

// ---------------- bilinear gather on planar G: LDS meta, bounded unroll ----------
__global__ __launch_bounds__(256, 4) void k_sample(const short* __restrict__ G,
    const int2* __restrict__ moff, const float4* __restrict__ mw,
    const float* __restrict__ bias, short* __restrict__ cand){
  __shared__ int2 smo[216];
  __shared__ float4 smw[216];
  int id = blockIdx.x;                        // 1024 blocks
  int sw = (id & 7)*128 + (id >> 3);          // XCD band swizzle
  int tid = threadIdx.x;
  int pbase = sw*8;
  if (tid < 216){
    smo[tid] = moff[pbase*27 + tid];
    smw[tid] = mw[pbase*27 + tid];
  }
  __syncthreads();
  int lp = (tid >> 6)*2 + ((tid >> 5) & 1);   // local pixel 0..7
  int p = pbase + lp;
  int c8 = (tid & 31)*8;
  float av[3][8];
  {
    float4 b0 = *(const float4*)(bias + c8);
    float4 b1 = *(const float4*)(bias + c8 + 4);
    #pragma unroll
    for (int h2 = 0; h2 < 3; ++h2){
      av[h2][0]=b0.x; av[h2][1]=b0.y; av[h2][2]=b0.z; av[h2][3]=b0.w;
      av[h2][4]=b1.x; av[h2][5]=b1.y; av[h2][6]=b1.z; av[h2][7]=b1.w;
    }
  }
  #pragma unroll
  for (int hyp = 0; hyp < 3; ++hyp){
    #pragma unroll 3
    for (int tap = 0; tap < 9; ++tap){
      int idx = lp*27 + hyp*9 + tap;
      int2 o = smo[idx];
      float4 wv = smw[idx];
      const short* r0 = (const short*)((const char*)G + o.x) + c8;
      const short* r1 = (const short*)((const char*)G + o.y) + c8;
      short8 v00 = *(const short8*)r0;
      short8 v01 = *(const short8*)(r0 + 256);
      short8 v10 = *(const short8*)r1;
      short8 v11 = *(const short8*)(r1 + 256);
      #pragma unroll
      for (int e = 0; e < 8; ++e){
        float s = wv.x*bf2f(v00[e]) + wv.y*bf2f(v01[e]);
        s += wv.z*bf2f(v10[e]) + wv.w*bf2f(v11[e]);
        av[hyp][e] += s;
      }
    }
  }
  #pragma unroll
  for (int hyp = 0; hyp < 3; ++hyp){
    short8 o;
    #pragma unroll
    for (int e = 0; e < 8; ++e) o[e] = f2bf(av[hyp][e]);
    *(short8*)(cand + ((size_t)hyp*NPIX + p)*256 + c8) = o;
  }
}

// ---------------- sum 3 partials + bias -> t ; per-block GN partial stats ----------------
__global__ void k_sum3stat(const float* __restrict__ PG, const float* __restrict__ bias,
    float* __restrict__ t, float* __restrict__ spart){
  int p0 = blockIdx.x * 8;
  int c = threadIdx.x;
  float bb = bias[c];
  float s = 0.f, s2 = 0.f;
  #pragma unroll
  for (int pp = 0; pp < 8; ++pp){
    size_t idx = (size_t)(p0+pp)*256 + c;
    float v = PG[idx] + PG[idx + 2097152] + PG[idx + 4194304] + bb;
    t[idx] = v;
    s += v; s2 = fmaf(v, v, s2);
  }
  s  += __shfl_xor(s, 1, 64);  s  += __shfl_xor(s, 2, 64);  s  += __shfl_xor(s, 4, 64);
  s2 += __shfl_xor(s2, 1, 64); s2 += __shfl_xor(s2, 2, 64); s2 += __shfl_xor(s2, 4, 64);
  if ((c & 7) == 0){
    int b = p0 >> 12;
    int bg = b*32 + (c >> 3);
    int blk = blockIdx.x & 511;
    spart[(size_t)(bg*512 + blk)*2]     = s;
    spart[(size_t)(bg*512 + blk)*2 + 1] = s2;
  }
}

__global__ void k_gnfin(const float* __restrict__ spart, float* __restrict__ stat){
  int bg = blockIdx.x;
  const float* sp = spart + (size_t)bg*1024;
  float s = 0.f, s2 = 0.f;
  for (int i = threadIdx.x; i < 512; i += 256){
    s += sp[i*2]; s2 += sp[i*2+1];
  }
  s = wsum64(s); s2 = wsum64(s2);
  __shared__ float rs[4], rs2[4];
  int wid = threadIdx.x >> 6;
  if ((threadIdx.x & 63) == 0){ rs[wid] = s; rs2[wid] = s2; }
  __syncthreads();
  if (threadIdx.x == 0){
    float S = rs[0]+rs[1]+rs[2]+rs[3];
    float S2 = rs2[0]+rs2[1]+rs2[2]+rs2[3];
    float mean = S * (1.f/32768.f);
    float var = S2 * (1.f/32768.f) - mean*mean;
    stat[bg*2]   = mean;
    stat[bg*2+1] = rsqrtf(var + 1e-5f);
  }
}

// ---------------- GN+relu fused into final 1x1 projection, NCHW fp32 out ----------------
__global__ __launch_bounds__(256) void k_gnproj(const float* __restrict__ t,
    const float* __restrict__ stat, const float* __restrict__ gng,
    const float* __restrict__ gnb, const short* __restrict__ w2,
    const float* __restrict__ b2, float* __restrict__ out){
  __shared__ float cst[64*132];          // aliased: bf16 A tile (64x256) during GEMM
  __shared__ alignas(16) short sB[2][128*32];
  short* sA = (short*)cst;
  int tid = threadIdx.x;
  int m0 = blockIdx.x*64;
  int b = m0 >> 12;
  int srow = tid >> 2, sch = (tid & 3)*8;
  const short* Bgp = w2 + (size_t)(blockIdx.y*128 + srow)*256 + sch;
  short* sBd = &sB[0][srow*32 + sch];
  gl_lds(Bgp, sBd);
  gl_lds(Bgp + (size_t)64*256, sBd + 2048);
  // GN + relu -> bf16 A tile
  #pragma unroll 4
  for (int it = 0; it < 16; ++it){
    int c = it*256 + tid;
    int row = c >> 6;
    int col = (c & 63)*4;
    int g4 = col >> 3;
    float mean = stat[(b*32+g4)*2], rstd = stat[(b*32+g4)*2+1];
    float4 v = *(const float4*)(t + (size_t)(m0+row)*256 + col);
    float4 gg = *(const float4*)(gng + col);
    float4 bbv = *(const float4*)(gnb + col);
    short4_t o;
    o[0] = f2bf(fmaxf((v.x - mean)*rstd*gg.x + bbv.x, 0.f));
    o[1] = f2bf(fmaxf((v.y - mean)*rstd*gg.y + bbv.y, 0.f));
    o[2] = f2bf(fmaxf((v.z - mean)*rstd*gg.z + bbv.z, 0.f));
    o[3] = f2bf(fmaxf((v.w - mean)*rstd*gg.w + bbv.w, 0.f));
    *(short4_t*)&sA[row*256 + col] = o;
  }
  // GEMM: BM=64, BN=128: waves 2x2, WM=32, AF=2; A from sA, B dbuf
  int w = tid >> 6, l = tid & 63;
  int wr = w & 1, wc = w >> 1;
  int ml = l & 15, g = l >> 4;
  f32x4 acc[2][4];
  #pragma unroll
  for (int i = 0; i < 2; ++i)
    #pragma unroll
    for (int j = 0; j < 4; ++j) acc[i][j] = (f32x4){0.f,0.f,0.f,0.f};
  int buf = 0;
  for (int kt = 0; kt < 8; ++kt){
    __syncthreads();
    if (kt + 1 < 8){
      gl_lds(Bgp + (kt+1)*32, sBd + (buf^1)*4096);
      gl_lds(Bgp + (size_t)64*256 + (kt+1)*32, sBd + (buf^1)*4096 + 2048);
    }
    short8 af[2], bq[4];
    #pragma unroll
    for (int i = 0; i < 2; ++i)
      af[i] = *(const short8*)&sA[(wr*32 + i*16 + ml)*256 + kt*32 + g*8];
    #pragma unroll
    for (int j = 0; j < 4; ++j)
      bq[j] = *(const short8*)&sB[buf][(wc*64 + j*16 + ml)*32 + g*8];
    #pragma unroll
    for (int i = 0; i < 2; ++i)
      #pragma unroll
      for (int j = 0; j < 4; ++j)
        acc[i][j] = __builtin_amdgcn_mfma_f32_16x16x32_bf16(af[i], bq[j], acc[i][j], 0, 0, 0);
    buf ^= 1;
  }
  __syncthreads();   // sA dead; reuse as cst
  #pragma unroll
  for (int fm = 0; fm < 2; ++fm)
    #pragma unroll
    for (int fn = 0; fn < 4; ++fn)
      #pragma unroll
      for (int r = 0; r < 4; ++r){
        int cl = wc*64 + fn*16 + ml;
        cst[(wr*32 + fm*16 + g*4 + r)*132 + cl] = acc[fm][fn][r] + b2[blockIdx.y*128 + cl];
      }
  __syncthreads();
  int hw0 = m0 & 4095;
  int o = tid >> 1, seg = (tid & 1)*32;
  float* op = out + (((size_t)(b*256 + blockIdx.y*128 + o)) << 12) + hw0 + seg;
  #pragma unroll
  for (int i = 0; i < 32; i += 4){
    float4 vv = {cst[(seg+i)*132+o], cst[(seg+i+1)*132+o],
                 cst[(seg+i+2)*132+o], cst[(seg+i+3)*132+o]};
    *(float4*)(op + i) = vv;
  }
}

// ---------------- launch ----------------
extern "C" void kernel_launch(void* const* d_in, const int* in_sizes, int n_in,
                              void* d_out, int out_size, void* d_ws, size_t ws_size,
                              hipStream_t stream){
  (void)in_sizes; (void)n_in; (void)out_size; (void)ws_size;
  const float* features   = (const float*)d_in[0];
  const float* ap_w1      = (const float*)d_in[1];
  const float* ap_b1      = (const float*)d_in[2];
  const float* ap_w2      = (const float*)d_in[3];
  const float* ap_b2      = (const float*)d_in[4];
  const float* freq       = (const float*)d_in[5];
  const float* ae_w1      = (const float*)d_in[6];
  const float* ae_b1      = (const float*)d_in[7];
  const float* ae_ln_g    = (const float*)d_in[8];
  const float* ae_ln_b    = (const float*)d_in[9];
  const float* ae_w2      = (const float*)d_in[10];
  const float* ae_b2      = (const float*)d_in[11];
  const float* dc_w       = (const float*)d_in[12];
  const float* dc_b       = (const float*)d_in[13];
  const float* attn_in_w  = (const float*)d_in[14];
  const float* attn_in_b  = (const float*)d_in[15];
  const float* attn_out_w = (const float*)d_in[16];
  const float* attn_out_b = (const float*)d_in[17];
  const float* ja_w1      = (const float*)d_in[18];
  const float* ja_b1      = (const float*)d_in[19];
  const float* ja_w2      = (const float*)d_in[20];
  const float* ja_b2      = (const float*)d_in[21];
  const float* op_w1      = (const float*)d_in[22];
  const float* op_b1      = (const float*)d_in[23];
  const float* gn_g       = (const float*)d_in[24];
  const float* gn_b       = (const float*)d_in[25];
  const float* op_w2      = (const float*)d_in[26];
  const float* op_b2      = (const float*)d_in[27];

  char* base = (char*)d_ws;
  #define ALLOC(ty, name, elems) ty* name = (ty*)base; base += (size_t)(elems)*sizeof(ty);
  ALLOC(short, Bdc,     2304*256)
  ALLOC(short, B2op,    256*2304)
  ALLOC(short, B3ap,    640*512)
  ALLOC(short, inw_bf,  768*256)
  ALLOC(short, wot_bf,  256*256)
  ALLOC(short, jw1_bf,  256*320)
  ALLOC(short, jw2_bf,  256*256)
  ALLOC(short, wop2_bf, 256*256)
  ALLOC(short, A3,      8192*512)    // [hi|lo] per pixel; G reads hi half (lda=512)
  ALLOC(short, Gbuf,    24576*768)   // serves: planar G -> KV/Q -> PG(fp32 x3)
  ALLOC(short, gguard,  256)         // OOB-wrap guard for k_sample edge reads (512B)
  ALLOC(float, T_ap,    8192*640)
  ALLOC(short, cand_bf, 3*8192*256)
  ALLOC(short, gateA,   8192*320)
  ALLOC(short, hid_bf,  8192*256)
  ALLOC(short, enh_pad, 2*4356*256)  // (B,66,66,256); ring zeroed each call, interior rewritten
  ALLOC(float, tbuf,    8192*256)
  ALLOC(float, gstat,   128)
  ALLOC(float, spart,   65536)
  ALLOC(int,   moffb,   2*NPIX*27)
  ALLOC(float, mwb,     4*NPIX*27)
  #undef ALLOC
  (void)gguard;
  short* KVbuf = Gbuf;                      // 24576*512 bf16
  short* Qbuf  = Gbuf + (size_t)24576*512;  // 8192*256 bf16
  float* PG    = (float*)Gbuf;              // 3 x 8192*256 fp32 partials
  int2*  moff  = (int2*)moffb;
  float4* mwv  = (float4*)mwb;

  k_prepall<<<4258, 256, 0, stream>>>(dc_w, op_w1, ap_w1, features,
      attn_in_w, attn_out_w, ja_w1, ja_w2, op_w2,
      enh_pad, Bdc, B2op, B3ap, A3,
      inw_bf, wot_bf, jw1_bf, jw2_bf, wop2_bf);

  // G (tap-planar, K=256) + T_ap (K=512) in one dispatch
  k_mainA<<<dim3(64,23), 256, 0, stream>>>(A3, Bdc, B3ap, Gbuf, T_ap);
  k_aph1enc<<<2048, 256, 0, stream>>>(T_ap, ap_b1, ap_w2, ap_b2, freq,
                                      ae_w1, ae_b1, ae_ln_g, ae_ln_b, ae_w2, ae_b2,
                                      gateA, moff, mwv);
  k_sample<<<1024, 256, 0, stream>>>(Gbuf, moff, mwv, dc_b, cand_bf);
  // Q + KV projections in one dispatch
  k_qkv<<<dim3(192,5), 256, 0, stream>>>(cand_bf, inw_bf, attn_in_b, KVbuf, Qbuf);
  // attention + output projection fused -> gateA cols 0..255
  k_attnproj<<<dim3(128,4), 256, 0, stream>>>(Qbuf, KVbuf, wot_bf, attn_out_b, gateA);
  // hid = relu(gateA x ja_w1^T + b1)
  k_gemml<2,64,64><<<dim3(128,4), 256, 0, stream>>>(gateA, jw1_bf, hid_bf, ja_b1, nullptr, 320, 256);
  // enh = fused * (1 + sigmoid(hid x ja_w2^T + b2)) -> padded NHWC
  k_gemml<6,64,64><<<dim3(128,4), 256, 0, stream>>>(hid_bf, jw2_bf, enh_pad, ja_b2, gateA, 256, 256);
  // conv3x3(enh_pad, op_w1): split-K=3 partials then fused sum+bias+GN-stats
  k_igconv<<<dim3(128,2,3), 256, 0, stream>>>(enh_pad, B2op, PG);
  k_sum3stat<<<1024, 256, 0, stream>>>(PG, op_b1, tbuf, spart);
  k_gnfin<<<64, 256, 0, stream>>>(spart, gstat);
  // GN + relu + out-projection fused, NCHW fp32
  k_gnproj<<<dim3(128,2), 256, 0, stream>>>(tbuf, gstat, gn_g, gn_b, wop2_bf, op_b2,
                                            (float*)d_out);
}